// Round 13
// baseline (818.087 us; speedup 1.0000x reference)
//
#include <hip/hip_runtime.h>
#include <hip/hip_bf16.h>

// Problem constants
#define G_NUM 1024
#define NPG   1024
#define HID   128
#define TILE_ROWS 32
#define TILES_PER_WG 32    // 1 graph per WG, grid 1024 = exactly 4 WGs/CU
#define GRAPHS_PER_WG 1

typedef __attribute__((ext_vector_type(8))) short   short8;   // 8 x bf16 (4 VGPRs)
typedef __attribute__((ext_vector_type(4))) float   floatx4;  // MFMA acc

__device__ __forceinline__ unsigned short f2bf(float f) {
  unsigned int u = __float_as_uint(f);
  u += 0x7fffu + ((u >> 16) & 1u);   // round-to-nearest-even
  return (unsigned short)(u >> 16);
}

__device__ __forceinline__ unsigned int cvt_pk_bf16(float lo, float hi) {
  unsigned int r;
  asm("v_cvt_pk_bf16_f32 %0, %1, %2" : "=v"(r) : "v"(lo), "v"(hi));
  return r;
}

// LDS-only barrier: orders ds ops across the WG without draining vmcnt
// (global loads/stores stay in flight across it) — round-8's 25% win.
__device__ __forceinline__ void wg_barrier_lds() {
  asm volatile("s_waitcnt lgkmcnt(0)\n\ts_barrier" ::: "memory");
}

// softplus via v_exp_f32 / v_log_f32 (exp2/log2)
__device__ __forceinline__ float softplusf(float x) {
  float t = exp2f(-fabsf(x) * 1.44269504f);
  return fmaxf(x, 0.f) + 0.69314718f * log2f(1.f + t);
}

// ---------------------------------------------------------------------------
// ws layout (bytes):
//   Wt1   @ 0      : [256][128] bf16, Wt1[c][k] = (c<128 ? d_w1 : u_w1)[k][c%128]
//   W2t   @ 65536  : [32][256]  bf16, block-diag 2nd-layer weights (transposed)
//   b1cat @ 81920  : f32[256]  (d_b1 || u_b1)
//   b2cat @ 82944  : f32[32]   (d_b2 || u_b2 || 0-pad)
// ---------------------------------------------------------------------------
__global__ void prep_kernel(const float* __restrict__ d_w1, const float* __restrict__ d_b1,
                            const float* __restrict__ d_w2,
                            const float* __restrict__ u_w1, const float* __restrict__ u_b1,
                            const float* __restrict__ u_w2,
                            const float* __restrict__ d_b2, const float* __restrict__ u_b2,
                            unsigned short* __restrict__ Wt1, unsigned short* __restrict__ W2t,
                            float* __restrict__ b1cat, float* __restrict__ b2cat)
{
  int id = blockIdx.x * blockDim.x + threadIdx.x;
  int stride = gridDim.x * blockDim.x;
  for (int idx = id; idx < 32768; idx += stride) {
    int c = idx >> 7, k = idx & 127;
    float v = (c < 128) ? d_w1[k * 128 + c] : u_w1[k * 128 + (c - 128)];
    Wt1[idx] = f2bf(v);
  }
  for (int idx = id; idx < 8192; idx += stride) {
    int c2 = idx >> 8, h = idx & 255;
    float v = 0.f;
    if (h < 128) { if (c2 < 2) v = d_w2[h * 2 + c2]; }
    else         { if (c2 >= 2 && c2 < 18) v = u_w2[(h - 128) * 16 + (c2 - 2)]; }
    W2t[idx] = f2bf(v);
  }
  for (int idx = id; idx < 256; idx += stride)
    b1cat[idx] = (idx < 128) ? d_b1[idx] : u_b1[idx - 128];
  for (int idx = id; idx < 32; idx += stride)
    b2cat[idx] = (idx < 2) ? d_b2[idx] : ((idx < 18) ? u_b2[idx - 2] : 0.f);
}

// ---------------------------------------------------------------------------
// Fused main kernel, round 13: round-8 body, re-packed for 4 WGs/CU.
//   * grid 1024 x 1 graph; LDS single-buffered sH + sC1 = 27.6 KB
//     -> 4 WGs/CU resident (round 12's 51 KB allowed only 3 -> straggler
//     phase at 1 WG/CU caused the regression).
//   * 2 lgkm-only barriers/tile:
//       P1 {A(t)->sH ; prefetch t+2 ; C(t-1)<-sC1} ; bar ;
//       P2 {B(t): read sH -> MFMA -> DPP -> write sC1} ; bar
//     Hazards: sH  W(t)->R(t) by bar1(t);  R(t)->W(t+1) by bar2(t).
//              sC1 W(t)->R(t) by bar2(t);  R(t)->W(t+1) by bar1(t+1).
//   * __launch_bounds__(256,4): pins the 128-VGPR allocation the compiler
//     already produced under (256,2) (round-12 counter: VGPR_Count=128).
// ---------------------------------------------------------------------------
__global__ __launch_bounds__(256, 4) void fused_kernel(
    const float* __restrict__ H,
    const unsigned short* __restrict__ Wt1, const unsigned short* __restrict__ W2t,
    const float* __restrict__ b1cat, const float* __restrict__ b2cat,
    const float* __restrict__ s_w1, const float* __restrict__ s_b1,
    const float* __restrict__ s_w2, const float* __restrict__ s_b2,
    float* __restrict__ out)
{
  __shared__ __align__(16) unsigned short sH [TILE_ROWS * 128];   // 8 KB, swizzled
  __shared__ __align__(16) unsigned short sC1[TILE_ROWS * 256];   // 16 KB, swizzled
  __shared__ __align__(16) float sX[768];                         // 3 KB tail scratch

  const int tid  = threadIdx.x;
  const int g    = blockIdx.x;      // one graph per WG
  const int lane = tid & 63;
  const int w    = tid >> 6;        // wave 0..3
  const int l15  = lane & 15;
  const int l4   = lane >> 4;

  float* outD = out;                 // [N][2]
  float* outU = out + 2097152;       // [N][16]
  float* outS = out + 18874368;      // [G][8]

  // ---- hoisted weights (resident in unified VGPR/AGPR file) ----
  short8 b1f[4][4];
  float  b1b[4];
#pragma unroll
  for (int nt = 0; nt < 4; ++nt) {
    int c = 64 * w + 16 * nt + l15;
    b1b[nt] = b1cat[c];
#pragma unroll
    for (int ks = 0; ks < 4; ++ks)
      b1f[nt][ks] = *(const short8*)(Wt1 + c * 128 + 32 * ks + 8 * l4);
  }
  const int r0 = 16 * (w >> 1);     // layer-2: wave quadrant rows
  const int c0 = 16 * (w & 1);      //                  ... cols
  short8 w2f[8];
#pragma unroll
  for (int s8 = 0; s8 < 8; ++s8)
    w2f[s8] = *(const short8*)(W2t + (c0 + l15) * 256 + 32 * s8 + 8 * l4);
  const float b2v = b2cat[c0 + l15];

  // DPP transpose lane constants
  const unsigned selw = (l15 & 1) ? 0x03020706u : 0x05040100u;
  const bool hi2 = (l15 & 2) != 0;

  const float* Hb = H + (long)g * (NPG * HID);

  float4 psum = make_float4(0.f, 0.f, 0.f, 0.f);   // per-lane pool partial (4 cols)

  // ---- depth-2 prefetch: svA = tile 0, svB = tile 1 ----
  float4 svA[4], svB[4];
#pragma unroll
  for (int i = 0; i < 4; ++i) svA[i] = *(const float4*)(Hb + i * 1024 + tid * 4);
#pragma unroll
  for (int i = 0; i < 4; ++i) svB[i] = *(const float4*)(Hb + 4096 + i * 1024 + tid * 4);

  // Region C: layer-2 MFMA of tile tc from sC1 + direct global stores.
  // (reads interleaved 1:1 with MFMAs — compiler pipelines the lgkm waits)
  auto regionC = [&](int tc) {
    floatx4 acc2 = {b2v, b2v, b2v, b2v};            // bias in C-in
#pragma unroll
    for (int s8 = 0; s8 < 8; ++s8) {
      int r = r0 + l15;
      int bo = r * 512 + 64 * s8 + 16 * l4;
      bo ^= (r & 7) << 4;
      short8 a2 = *(const short8*)((const char*)sC1 + bo);
      acc2 = __builtin_amdgcn_mfma_f32_16x16x32_bf16(a2, w2f[s8], acc2, 0, 0, 0);
    }
    long nodebase = (long)g * NPG + tc * TILE_ROWS + r0 + 4 * l4;
    if (c0 == 0) {          // wave-uniform: cols 0..15 = d(0,1) + U(0..13)
#pragma unroll
      for (int q = 0; q < 4; ++q) {
        float v = acc2[q];
        long node = nodebase + q;
        if (l15 < 2) outD[node * 2 + l15] = softplusf(v);
        else         outU[node * 16 + (l15 - 2)] = v;
      }
    } else {                // cols 16..31 = U(14,15) + pad
#pragma unroll
      for (int q = 0; q < 4; ++q) {
        long node = nodebase + q;
        if (l15 < 2) outU[node * 16 + 14 + l15] = acc2[q];
      }
    }
  };

  // body: P1 {A(t)->sH ; prefetch ; C(t-1)} ; bar ; P2 {B(t)->sC1} ; bar
  auto body = [&](float4 (&cur)[4], int t) {
    // ---- P1a: consume prefetched regs -> pool partials + bf16 swizzled sH ----
#pragma unroll
    for (int i = 0; i < 4; ++i) {
      float4 v = cur[i];
      psum.x += v.x; psum.y += v.y; psum.z += v.z; psum.w += v.w;
      int row = i * 8 + (tid >> 5);
      int bo = row * 256 + (tid & 31) * 8;
      bo ^= (row & 7) << 4;
      uint2 p;
      p.x = cvt_pk_bf16(v.x, v.y);
      p.y = cvt_pk_bf16(v.z, v.w);
      *(uint2*)((char*)sH + bo) = p;
    }
    if (t + 2 < TILES_PER_WG) {
      const float* nb = Hb + (t + 2) * (TILE_ROWS * HID);
#pragma unroll
      for (int i = 0; i < 4; ++i) cur[i] = *(const float4*)(nb + i * 1024 + tid * 4);
    }
    // ---- P1b: layer-2 of previous tile (sC1 read; disjoint from sH write) ----
    if (t > 0) regionC(t - 1);
    wg_barrier_lds();   // bar1: sH ready for B; sC1 free for B's writes

    // ---- P2: layer-1 MFMA (weights in regs, bias in C-in) + DPP epilogue ----
    floatx4 acc[2][4];
#pragma unroll
    for (int mt = 0; mt < 2; ++mt)
#pragma unroll
      for (int nt = 0; nt < 4; ++nt)
        acc[mt][nt] = (floatx4){b1b[nt], b1b[nt], b1b[nt], b1b[nt]};

#pragma unroll
    for (int ks = 0; ks < 4; ++ks) {
      short8 a[2];
#pragma unroll
      for (int mt = 0; mt < 2; ++mt) {
        int row = 16 * mt + l15;
        int bo = row * 256 + 64 * ks + 16 * l4;
        bo ^= (row & 7) << 4;
        a[mt] = *(const short8*)((const char*)sH + bo);
      }
#pragma unroll
      for (int mt = 0; mt < 2; ++mt)
#pragma unroll
        for (int nt = 0; nt < 4; ++nt)
          acc[mt][nt] = __builtin_amdgcn_mfma_f32_16x16x32_bf16(a[mt], b1f[nt][ks], acc[mt][nt], 0, 0, 0);
    }

    // Epilogue: per 4x4 quad sub-block, transpose in VALU, one ds_write_b64.
#pragma unroll
    for (int mt = 0; mt < 2; ++mt) {
#pragma unroll
      for (int nt = 0; nt < 4; ++nt) {
        float v0 = fmaxf(acc[mt][nt][0], 0.f);
        float v1 = fmaxf(acc[mt][nt][1], 0.f);
        float v2 = fmaxf(acc[mt][nt][2], 0.f);
        float v3 = fmaxf(acc[mt][nt][3], 0.f);
        unsigned A = cvt_pk_bf16(v0, v1);          // rows q0,q1 (own col)
        unsigned B = cvt_pk_bf16(v2, v3);          // rows q2,q3
        unsigned An = (unsigned)__builtin_amdgcn_mov_dpp((int)A, 0xB1, 0xF, 0xF, true); // lane^1
        unsigned Bn = (unsigned)__builtin_amdgcn_mov_dpp((int)B, 0xB1, 0xF, 0xF, true);
        unsigned WA = __builtin_amdgcn_perm(An, A, selw);
        unsigned WB = __builtin_amdgcn_perm(Bn, B, selw);
        unsigned WAs = (unsigned)__builtin_amdgcn_mov_dpp((int)WA, 0x4E, 0xF, 0xF, true); // lane^2
        unsigned WBs = (unsigned)__builtin_amdgcn_mov_dpp((int)WB, 0x4E, 0xF, 0xF, true);
        uint2 o;
        o.x = hi2 ? WBs : WA;
        o.y = hi2 ? WB  : WAs;
        int row = 16 * mt + 4 * l4 + (l15 & 3);
        int cb  = 64 * w + 16 * nt + (l15 & 12);
        int bo = row * 512 + cb * 2;
        bo ^= (row & 7) << 4;
        *(uint2*)((char*)sC1 + bo) = o;
      }
    }
    wg_barrier_lds();   // bar2: sC1 ready for C(t); sH free for A(t+1)
  };

  for (int t = 0; t < TILES_PER_WG; t += 2) {
    body(svA, t);       // even tiles live in svA
    body(svB, t + 1);   // odd  tiles live in svB
  }
  regionC(TILES_PER_WG - 1);   // drain last tile (bar2 of tile 31 passed)

  // ---- tail: s-head for this graph (exact f32) ----
  {
    float4 p = psum;
    __syncthreads();
    p.x += __shfl_xor(p.x, 32);
    p.y += __shfl_xor(p.y, 32);
    p.z += __shfl_xor(p.z, 32);
    p.w += __shfl_xor(p.w, 32);
    if (lane < 32) *(float4*)&sX[w * 128 + lane * 4] = p;   // per-wave col partials
    __syncthreads();
    if (tid < 128) {                      // pool[c] = sum over 4 waves
      float pc = sX[tid] + sX[128 + tid] + sX[256 + tid] + sX[384 + tid];
      sX[512 + tid] = pc;
    }
    __syncthreads();
    if (tid < 128) {
      float a = s_b1[tid];
      const float inv = 1.f / 1024.f;
#pragma unroll 8
      for (int k = 0; k < 128; ++k)
        a = fmaf(sX[512 + k] * inv, s_w1[k * 128 + tid], a);
      sX[640 + tid] = fmaxf(a, 0.f);
    }
    __syncthreads();
    if (tid < 8) {
      float a = s_b2[tid];
#pragma unroll 8
      for (int h = 0; h < 128; ++h)
        a = fmaf(sX[640 + h], s_w2[h * 8 + tid], a);
      outS[(long)g * 8 + tid] = softplusf(a);
    }
  }
}

// ---------------------------------------------------------------------------
extern "C" void kernel_launch(void* const* d_in, const int* in_sizes, int n_in,
                              void* d_out, int out_size, void* d_ws, size_t ws_size,
                              hipStream_t stream)
{
  const float* H    = (const float*)d_in[0];
  // d_in[1] = batch (int32) — equal sorted segments, structure is assumed
  const float* d_w1 = (const float*)d_in[2];
  const float* d_b1 = (const float*)d_in[3];
  const float* d_w2 = (const float*)d_in[4];
  const float* d_b2 = (const float*)d_in[5];
  const float* u_w1 = (const float*)d_in[6];
  const float* u_b1 = (const float*)d_in[7];
  const float* u_w2 = (const float*)d_in[8];
  const float* u_b2 = (const float*)d_in[9];
  const float* s_w1 = (const float*)d_in[10];
  const float* s_b1 = (const float*)d_in[11];
  const float* s_w2 = (const float*)d_in[12];
  const float* s_b2 = (const float*)d_in[13];

  unsigned short* Wt1   = (unsigned short*)d_ws;
  unsigned short* W2t   = (unsigned short*)((char*)d_ws + 65536);
  float*          b1cat = (float*)((char*)d_ws + 81920);
  float*          b2cat = (float*)((char*)d_ws + 82944);

  hipLaunchKernelGGL(prep_kernel, dim3(64), dim3(256), 0, stream,
                     d_w1, d_b1, d_w2, u_w1, u_b1, u_w2, d_b2, u_b2,
                     Wt1, W2t, b1cat, b2cat);

  hipLaunchKernelGGL(fused_kernel, dim3(G_NUM), dim3(256), 0, stream,
                     H, Wt1, W2t, b1cat, b2cat, s_w1, s_b1, s_w2, s_b2,
                     (float*)d_out);
}

// Round 14
// 206.420 us; speedup vs baseline: 3.9632x; 3.9632x over previous
//
#include <hip/hip_runtime.h>
#include <hip/hip_bf16.h>

// Problem constants
#define G_NUM 1024
#define NPG   1024
#define HID   128
#define TILE_ROWS 32
#define TILES_PER_WG 32    // 1 graph per WG, grid 1024 = exactly 4 WGs/CU
#define GRAPHS_PER_WG 1

typedef __attribute__((ext_vector_type(8))) short   short8;   // 8 x bf16 (4 VGPRs)
typedef __attribute__((ext_vector_type(4))) float   floatx4;  // MFMA acc

__device__ __forceinline__ unsigned short f2bf(float f) {
  unsigned int u = __float_as_uint(f);
  u += 0x7fffu + ((u >> 16) & 1u);   // round-to-nearest-even
  return (unsigned short)(u >> 16);
}

__device__ __forceinline__ unsigned int cvt_pk_bf16(float lo, float hi) {
  unsigned int r;
  asm("v_cvt_pk_bf16_f32 %0, %1, %2" : "=v"(r) : "v"(lo), "v"(hi));
  return r;
}

// LDS-only barrier: orders ds ops across the WG without draining vmcnt
// (global loads/stores stay in flight across it) — round-8's 25% win.
__device__ __forceinline__ void wg_barrier_lds() {
  asm volatile("s_waitcnt lgkmcnt(0)\n\ts_barrier" ::: "memory");
}

// softplus via v_exp_f32 / v_log_f32 (exp2/log2)
__device__ __forceinline__ float softplusf(float x) {
  float t = exp2f(-fabsf(x) * 1.44269504f);
  return fmaxf(x, 0.f) + 0.69314718f * log2f(1.f + t);
}

// ---------------------------------------------------------------------------
// ws layout (bytes):
//   Wt1   @ 0      : [256][128] bf16, Wt1[c][k] = (c<128 ? d_w1 : u_w1)[k][c%128]
//   W2t   @ 65536  : [32][256]  bf16, block-diag 2nd-layer weights (transposed)
//   b1cat @ 81920  : f32[256]  (d_b1 || u_b1)
//   b2cat @ 82944  : f32[32]   (d_b2 || u_b2 || 0-pad)
// ---------------------------------------------------------------------------
__global__ void prep_kernel(const float* __restrict__ d_w1, const float* __restrict__ d_b1,
                            const float* __restrict__ d_w2,
                            const float* __restrict__ u_w1, const float* __restrict__ u_b1,
                            const float* __restrict__ u_w2,
                            const float* __restrict__ d_b2, const float* __restrict__ u_b2,
                            unsigned short* __restrict__ Wt1, unsigned short* __restrict__ W2t,
                            float* __restrict__ b1cat, float* __restrict__ b2cat)
{
  int id = blockIdx.x * blockDim.x + threadIdx.x;
  int stride = gridDim.x * blockDim.x;
  for (int idx = id; idx < 32768; idx += stride) {
    int c = idx >> 7, k = idx & 127;
    float v = (c < 128) ? d_w1[k * 128 + c] : u_w1[k * 128 + (c - 128)];
    Wt1[idx] = f2bf(v);
  }
  for (int idx = id; idx < 8192; idx += stride) {
    int c2 = idx >> 8, h = idx & 255;
    float v = 0.f;
    if (h < 128) { if (c2 < 2) v = d_w2[h * 2 + c2]; }
    else         { if (c2 >= 2 && c2 < 18) v = u_w2[(h - 128) * 16 + (c2 - 2)]; }
    W2t[idx] = f2bf(v);
  }
  for (int idx = id; idx < 256; idx += stride)
    b1cat[idx] = (idx < 128) ? d_b1[idx] : u_b1[idx - 128];
  for (int idx = id; idx < 32; idx += stride)
    b2cat[idx] = (idx < 2) ? d_b2[idx] : ((idx < 18) ? u_b2[idx - 2] : 0.f);
}

// ---------------------------------------------------------------------------
// Fused main kernel, round 14 = round 13 with __launch_bounds__(256,2).
// Round 13's (256,4) made the compiler TARGET 64 VGPRs -> b1f/w2f sunk to
// per-tile global re-reads (FETCH 2.6 GB, 818 µs) — the round-2 signature.
// Under (256,2) the compiler voluntarily allocates 128 VGPRs (measured
// r10/r11/r12), and 128 VGPRs ALREADY permits 4 waves/SIMD at runtime:
// launch_bounds is a compiler floor, not a runtime occupancy cap.
//   * grid 1024 x 1 graph; LDS single-buffered sH+sC1 = 27.6 KB -> LDS
//     allows 5 WGs/CU; VGPR=128 allows 4 -> 4 WGs/CU, balanced, no tail.
//   * 2 lgkm-only barriers/tile:
//       P1 {A(t)->sH ; prefetch t+2 ; C(t-1)<-sC1} ; bar ;
//       P2 {B(t): read sH -> MFMA -> DPP -> write sC1} ; bar
//     Hazards: sH  W(t)->R(t) by bar1(t);  R(t)->W(t+1) by bar2(t).
//              sC1 W(t)->R(t) by bar2(t);  R(t)->W(t+1) by bar1(t+1).
// ---------------------------------------------------------------------------
__global__ __launch_bounds__(256, 2) void fused_kernel(
    const float* __restrict__ H,
    const unsigned short* __restrict__ Wt1, const unsigned short* __restrict__ W2t,
    const float* __restrict__ b1cat, const float* __restrict__ b2cat,
    const float* __restrict__ s_w1, const float* __restrict__ s_b1,
    const float* __restrict__ s_w2, const float* __restrict__ s_b2,
    float* __restrict__ out)
{
  __shared__ __align__(16) unsigned short sH [TILE_ROWS * 128];   // 8 KB, swizzled
  __shared__ __align__(16) unsigned short sC1[TILE_ROWS * 256];   // 16 KB, swizzled
  __shared__ __align__(16) float sX[768];                         // 3 KB tail scratch

  const int tid  = threadIdx.x;
  const int g    = blockIdx.x;      // one graph per WG
  const int lane = tid & 63;
  const int w    = tid >> 6;        // wave 0..3
  const int l15  = lane & 15;
  const int l4   = lane >> 4;

  float* outD = out;                 // [N][2]
  float* outU = out + 2097152;       // [N][16]
  float* outS = out + 18874368;      // [G][8]

  // ---- hoisted weights (resident in unified VGPR/AGPR file) ----
  short8 b1f[4][4];
  float  b1b[4];
#pragma unroll
  for (int nt = 0; nt < 4; ++nt) {
    int c = 64 * w + 16 * nt + l15;
    b1b[nt] = b1cat[c];
#pragma unroll
    for (int ks = 0; ks < 4; ++ks)
      b1f[nt][ks] = *(const short8*)(Wt1 + c * 128 + 32 * ks + 8 * l4);
  }
  const int r0 = 16 * (w >> 1);     // layer-2: wave quadrant rows
  const int c0 = 16 * (w & 1);      //                  ... cols
  short8 w2f[8];
#pragma unroll
  for (int s8 = 0; s8 < 8; ++s8)
    w2f[s8] = *(const short8*)(W2t + (c0 + l15) * 256 + 32 * s8 + 8 * l4);
  const float b2v = b2cat[c0 + l15];

  // DPP transpose lane constants
  const unsigned selw = (l15 & 1) ? 0x03020706u : 0x05040100u;
  const bool hi2 = (l15 & 2) != 0;

  const float* Hb = H + (long)g * (NPG * HID);

  float4 psum = make_float4(0.f, 0.f, 0.f, 0.f);   // per-lane pool partial (4 cols)

  // ---- depth-2 prefetch: svA = tile 0, svB = tile 1 ----
  float4 svA[4], svB[4];
#pragma unroll
  for (int i = 0; i < 4; ++i) svA[i] = *(const float4*)(Hb + i * 1024 + tid * 4);
#pragma unroll
  for (int i = 0; i < 4; ++i) svB[i] = *(const float4*)(Hb + 4096 + i * 1024 + tid * 4);

  // Region C: layer-2 MFMA of tile tc from sC1 + direct global stores.
  // (reads interleaved 1:1 with MFMAs — compiler pipelines the lgkm waits)
  auto regionC = [&](int tc) {
    floatx4 acc2 = {b2v, b2v, b2v, b2v};            // bias in C-in
#pragma unroll
    for (int s8 = 0; s8 < 8; ++s8) {
      int r = r0 + l15;
      int bo = r * 512 + 64 * s8 + 16 * l4;
      bo ^= (r & 7) << 4;
      short8 a2 = *(const short8*)((const char*)sC1 + bo);
      acc2 = __builtin_amdgcn_mfma_f32_16x16x32_bf16(a2, w2f[s8], acc2, 0, 0, 0);
    }
    long nodebase = (long)g * NPG + tc * TILE_ROWS + r0 + 4 * l4;
    if (c0 == 0) {          // wave-uniform: cols 0..15 = d(0,1) + U(0..13)
#pragma unroll
      for (int q = 0; q < 4; ++q) {
        float v = acc2[q];
        long node = nodebase + q;
        if (l15 < 2) outD[node * 2 + l15] = softplusf(v);
        else         outU[node * 16 + (l15 - 2)] = v;
      }
    } else {                // cols 16..31 = U(14,15) + pad
#pragma unroll
      for (int q = 0; q < 4; ++q) {
        long node = nodebase + q;
        if (l15 < 2) outU[node * 16 + 14 + l15] = acc2[q];
      }
    }
  };

  // body: P1 {A(t)->sH ; prefetch ; C(t-1)} ; bar ; P2 {B(t)->sC1} ; bar
  auto body = [&](float4 (&cur)[4], int t) {
    // ---- P1a: consume prefetched regs -> pool partials + bf16 swizzled sH ----
#pragma unroll
    for (int i = 0; i < 4; ++i) {
      float4 v = cur[i];
      psum.x += v.x; psum.y += v.y; psum.z += v.z; psum.w += v.w;
      int row = i * 8 + (tid >> 5);
      int bo = row * 256 + (tid & 31) * 8;
      bo ^= (row & 7) << 4;
      uint2 p;
      p.x = cvt_pk_bf16(v.x, v.y);
      p.y = cvt_pk_bf16(v.z, v.w);
      *(uint2*)((char*)sH + bo) = p;
    }
    if (t + 2 < TILES_PER_WG) {
      const float* nb = Hb + (t + 2) * (TILE_ROWS * HID);
#pragma unroll
      for (int i = 0; i < 4; ++i) cur[i] = *(const float4*)(nb + i * 1024 + tid * 4);
    }
    // ---- P1b: layer-2 of previous tile (sC1 read; disjoint from sH write) ----
    if (t > 0) regionC(t - 1);
    wg_barrier_lds();   // bar1: sH ready for B; sC1 free for B's writes

    // ---- P2: layer-1 MFMA (weights in regs, bias in C-in) + DPP epilogue ----
    floatx4 acc[2][4];
#pragma unroll
    for (int mt = 0; mt < 2; ++mt)
#pragma unroll
      for (int nt = 0; nt < 4; ++nt)
        acc[mt][nt] = (floatx4){b1b[nt], b1b[nt], b1b[nt], b1b[nt]};

#pragma unroll
    for (int ks = 0; ks < 4; ++ks) {
      short8 a[2];
#pragma unroll
      for (int mt = 0; mt < 2; ++mt) {
        int row = 16 * mt + l15;
        int bo = row * 256 + 64 * ks + 16 * l4;
        bo ^= (row & 7) << 4;
        a[mt] = *(const short8*)((const char*)sH + bo);
      }
#pragma unroll
      for (int mt = 0; mt < 2; ++mt)
#pragma unroll
        for (int nt = 0; nt < 4; ++nt)
          acc[mt][nt] = __builtin_amdgcn_mfma_f32_16x16x32_bf16(a[mt], b1f[nt][ks], acc[mt][nt], 0, 0, 0);
    }

    // Epilogue: per 4x4 quad sub-block, transpose in VALU, one ds_write_b64.
#pragma unroll
    for (int mt = 0; mt < 2; ++mt) {
#pragma unroll
      for (int nt = 0; nt < 4; ++nt) {
        float v0 = fmaxf(acc[mt][nt][0], 0.f);
        float v1 = fmaxf(acc[mt][nt][1], 0.f);
        float v2 = fmaxf(acc[mt][nt][2], 0.f);
        float v3 = fmaxf(acc[mt][nt][3], 0.f);
        unsigned A = cvt_pk_bf16(v0, v1);          // rows q0,q1 (own col)
        unsigned B = cvt_pk_bf16(v2, v3);          // rows q2,q3
        unsigned An = (unsigned)__builtin_amdgcn_mov_dpp((int)A, 0xB1, 0xF, 0xF, true); // lane^1
        unsigned Bn = (unsigned)__builtin_amdgcn_mov_dpp((int)B, 0xB1, 0xF, 0xF, true);
        unsigned WA = __builtin_amdgcn_perm(An, A, selw);
        unsigned WB = __builtin_amdgcn_perm(Bn, B, selw);
        unsigned WAs = (unsigned)__builtin_amdgcn_mov_dpp((int)WA, 0x4E, 0xF, 0xF, true); // lane^2
        unsigned WBs = (unsigned)__builtin_amdgcn_mov_dpp((int)WB, 0x4E, 0xF, 0xF, true);
        uint2 o;
        o.x = hi2 ? WBs : WA;
        o.y = hi2 ? WB  : WAs;
        int row = 16 * mt + 4 * l4 + (l15 & 3);
        int cb  = 64 * w + 16 * nt + (l15 & 12);
        int bo = row * 512 + cb * 2;
        bo ^= (row & 7) << 4;
        *(uint2*)((char*)sC1 + bo) = o;
      }
    }
    wg_barrier_lds();   // bar2: sC1 ready for C(t); sH free for A(t+1)
  };

  for (int t = 0; t < TILES_PER_WG; t += 2) {
    body(svA, t);       // even tiles live in svA
    body(svB, t + 1);   // odd  tiles live in svB
  }
  regionC(TILES_PER_WG - 1);   // drain last tile (bar2 of tile 31 passed)

  // ---- tail: s-head for this graph (exact f32) ----
  {
    float4 p = psum;
    __syncthreads();
    p.x += __shfl_xor(p.x, 32);
    p.y += __shfl_xor(p.y, 32);
    p.z += __shfl_xor(p.z, 32);
    p.w += __shfl_xor(p.w, 32);
    if (lane < 32) *(float4*)&sX[w * 128 + lane * 4] = p;   // per-wave col partials
    __syncthreads();
    if (tid < 128) {                      // pool[c] = sum over 4 waves
      float pc = sX[tid] + sX[128 + tid] + sX[256 + tid] + sX[384 + tid];
      sX[512 + tid] = pc;
    }
    __syncthreads();
    if (tid < 128) {
      float a = s_b1[tid];
      const float inv = 1.f / 1024.f;
#pragma unroll 8
      for (int k = 0; k < 128; ++k)
        a = fmaf(sX[512 + k] * inv, s_w1[k * 128 + tid], a);
      sX[640 + tid] = fmaxf(a, 0.f);
    }
    __syncthreads();
    if (tid < 8) {
      float a = s_b2[tid];
#pragma unroll 8
      for (int h = 0; h < 128; ++h)
        a = fmaf(sX[640 + h], s_w2[h * 8 + tid], a);
      outS[(long)g * 8 + tid] = softplusf(a);
    }
  }
}

// ---------------------------------------------------------------------------
extern "C" void kernel_launch(void* const* d_in, const int* in_sizes, int n_in,
                              void* d_out, int out_size, void* d_ws, size_t ws_size,
                              hipStream_t stream)
{
  const float* H    = (const float*)d_in[0];
  // d_in[1] = batch (int32) — equal sorted segments, structure is assumed
  const float* d_w1 = (const float*)d_in[2];
  const float* d_b1 = (const float*)d_in[3];
  const float* d_w2 = (const float*)d_in[4];
  const float* d_b2 = (const float*)d_in[5];
  const float* u_w1 = (const float*)d_in[6];
  const float* u_b1 = (const float*)d_in[7];
  const float* u_w2 = (const float*)d_in[8];
  const float* u_b2 = (const float*)d_in[9];
  const float* s_w1 = (const float*)d_in[10];
  const float* s_b1 = (const float*)d_in[11];
  const float* s_w2 = (const float*)d_in[12];
  const float* s_b2 = (const float*)d_in[13];

  unsigned short* Wt1   = (unsigned short*)d_ws;
  unsigned short* W2t   = (unsigned short*)((char*)d_ws + 65536);
  float*          b1cat = (float*)((char*)d_ws + 81920);
  float*          b2cat = (float*)((char*)d_ws + 82944);

  hipLaunchKernelGGL(prep_kernel, dim3(64), dim3(256), 0, stream,
                     d_w1, d_b1, d_w2, u_w1, u_b1, u_w2, d_b2, u_b2,
                     Wt1, W2t, b1cat, b2cat);

  hipLaunchKernelGGL(fused_kernel, dim3(G_NUM), dim3(256), 0, stream,
                     H, Wt1, W2t, b1cat, b2cat, s_w1, s_b1, s_w2, s_b2,
                     (float*)d_out);
}

// Round 15
// 152.892 us; speedup vs baseline: 5.3507x; 1.3501x over previous
//
#include <hip/hip_runtime.h>
#include <hip/hip_bf16.h>

// Problem constants
#define G_NUM 1024
#define NPG   1024
#define HID   128
#define TILE_ROWS 32
#define TILES_PER_WG 64    // 2 graphs * 32 tiles, contiguous rows
#define GRAPHS_PER_WG 2

typedef __attribute__((ext_vector_type(8))) short   short8;   // 8 x bf16 (4 VGPRs)
typedef __attribute__((ext_vector_type(4))) float   floatx4;  // MFMA acc

__device__ __forceinline__ unsigned short f2bf(float f) {
  unsigned int u = __float_as_uint(f);
  u += 0x7fffu + ((u >> 16) & 1u);   // round-to-nearest-even
  return (unsigned short)(u >> 16);
}

__device__ __forceinline__ unsigned int cvt_pk_bf16(float lo, float hi) {
  unsigned int r;
  asm("v_cvt_pk_bf16_f32 %0, %1, %2" : "=v"(r) : "v"(lo), "v"(hi));
  return r;
}

// LDS-only barrier: orders ds_read/ds_write across the WG but does NOT
// drain vmcnt (global loads/stores stay in flight across it).
__device__ __forceinline__ void wg_barrier_lds() {
  asm volatile("s_waitcnt lgkmcnt(0)\n\ts_barrier" ::: "memory");
}

// softplus via v_exp_f32 / v_log_f32 (exp2/log2)
__device__ __forceinline__ float softplusf(float x) {
  float t = exp2f(-fabsf(x) * 1.44269504f);
  return fmaxf(x, 0.f) + 0.69314718f * log2f(1.f + t);
}

// ---------------------------------------------------------------------------
// ws layout (bytes):
//   Wt1   @ 0      : [256][128] bf16, Wt1[c][k] = (c<128 ? d_w1 : u_w1)[k][c%128]
//   W2t   @ 65536  : [32][256]  bf16, block-diag 2nd-layer weights (transposed)
//   b1cat @ 81920  : f32[256]  (d_b1 || u_b1)
//   b2cat @ 82944  : f32[32]   (d_b2 || u_b2 || 0-pad)
// ---------------------------------------------------------------------------
__global__ void prep_kernel(const float* __restrict__ d_w1, const float* __restrict__ d_b1,
                            const float* __restrict__ d_w2,
                            const float* __restrict__ u_w1, const float* __restrict__ u_b1,
                            const float* __restrict__ u_w2,
                            const float* __restrict__ d_b2, const float* __restrict__ u_b2,
                            unsigned short* __restrict__ Wt1, unsigned short* __restrict__ W2t,
                            float* __restrict__ b1cat, float* __restrict__ b2cat)
{
  int id = blockIdx.x * blockDim.x + threadIdx.x;
  int stride = gridDim.x * blockDim.x;
  for (int idx = id; idx < 32768; idx += stride) {
    int c = idx >> 7, k = idx & 127;
    float v = (c < 128) ? d_w1[k * 128 + c] : u_w1[k * 128 + (c - 128)];
    Wt1[idx] = f2bf(v);
  }
  for (int idx = id; idx < 8192; idx += stride) {
    int c2 = idx >> 8, h = idx & 255;
    float v = 0.f;
    if (h < 128) { if (c2 < 2) v = d_w2[h * 2 + c2]; }
    else         { if (c2 >= 2 && c2 < 18) v = u_w2[(h - 128) * 16 + (c2 - 2)]; }
    W2t[idx] = f2bf(v);
  }
  for (int idx = id; idx < 256; idx += stride)
    b1cat[idx] = (idx < 128) ? d_b1[idx] : u_b1[idx - 128];
  for (int idx = id; idx < 32; idx += stride)
    b2cat[idx] = (idx < 2) ? d_b2[idx] : ((idx < 18) ? u_b2[idx - 2] : 0.f);
}

// ---------------------------------------------------------------------------
// Fused main kernel, round 15 = round-8 champion VERBATIM (152.8 µs):
//   512 WGs x 2 graphs, 256 thr (4 waves), lgkm-only barriers, ONE barrier
//   per tile via double-buffered sH and sC1:
//     A(t)->sH[t&1] ; bar ; C(t-1)<-sC1[(t-1)&1] || B(t)->sC1[t&1]
//   Hazards: sH[b] write->read split by bar(t), next write by bar(t+1);
//   sC1[b] write->read split by bar(t+1), next write by bar(t+2).
// Rounds 9-14 (sH-elim, FIFO batching, reorder, 1024-grid 3-res, (256,4),
// single-buffer 2-bar) ALL regressed — each lever's failure mechanism is
// documented in the session log. This structure's constraints are mutually
// locking at 2 WGs/CU; keep it.
// ---------------------------------------------------------------------------
__global__ __launch_bounds__(256, 2) void fused_kernel(
    const float* __restrict__ H,
    const unsigned short* __restrict__ Wt1, const unsigned short* __restrict__ W2t,
    const float* __restrict__ b1cat, const float* __restrict__ b2cat,
    const float* __restrict__ s_w1, const float* __restrict__ s_b1,
    const float* __restrict__ s_w2, const float* __restrict__ s_b2,
    float* __restrict__ out)
{
  __shared__ __align__(16) unsigned short sH0 [TILE_ROWS * 128];  // 8 KB, swizzled
  __shared__ __align__(16) unsigned short sH1 [TILE_ROWS * 128];  // 8 KB
  __shared__ __align__(16) unsigned short sC1a[TILE_ROWS * 256];  // 16 KB, swizzled
  __shared__ __align__(16) unsigned short sC1b[TILE_ROWS * 256];  // 16 KB
  __shared__ __align__(16) float sX[768];                         // 3 KB tail scratch

  const int tid  = threadIdx.x;
  const int g0   = blockIdx.x * GRAPHS_PER_WG;
  const int lane = tid & 63;
  const int w    = tid >> 6;        // wave 0..3
  const int l15  = lane & 15;
  const int l4   = lane >> 4;

  float* outD = out;                 // [N][2]
  float* outU = out + 2097152;       // [N][16]
  float* outS = out + 18874368;      // [G][8]

  // ---- hoisted weights (resident: 64 + 32 VGPRs) ----
  short8 b1f[4][4];
  float  b1b[4];
#pragma unroll
  for (int nt = 0; nt < 4; ++nt) {
    int c = 64 * w + 16 * nt + l15;
    b1b[nt] = b1cat[c];
#pragma unroll
    for (int ks = 0; ks < 4; ++ks)
      b1f[nt][ks] = *(const short8*)(Wt1 + c * 128 + 32 * ks + 8 * l4);
  }
  const int r0 = 16 * (w >> 1);     // layer-2: wave quadrant rows
  const int c0 = 16 * (w & 1);      //                  ... cols
  short8 w2f[8];
#pragma unroll
  for (int s8 = 0; s8 < 8; ++s8)
    w2f[s8] = *(const short8*)(W2t + (c0 + l15) * 256 + 32 * s8 + 8 * l4);
  const float b2v = b2cat[c0 + l15];

  // DPP transpose lane constants
  const unsigned selw = (l15 & 1) ? 0x03020706u : 0x05040100u;
  const bool hi2 = (l15 & 2) != 0;

  const float* Hb = H + (long)g0 * (NPG * HID);

  float4 psum  = make_float4(0.f, 0.f, 0.f, 0.f);   // per-lane pool partial (4 cols)
  float4 pool0 = make_float4(0.f, 0.f, 0.f, 0.f);   // stashed graph-0 pool

  // ---- depth-2 prefetch: svA = tile 0, svB = tile 1 ----
  float4 svA[4], svB[4];
#pragma unroll
  for (int i = 0; i < 4; ++i) svA[i] = *(const float4*)(Hb + i * 1024 + tid * 4);
#pragma unroll
  for (int i = 0; i < 4; ++i) svB[i] = *(const float4*)(Hb + 4096 + i * 1024 + tid * 4);

  // Region C: layer-2 MFMA of tile tc from sCr + direct global stores.
  auto regionC = [&](const unsigned short* sCr, int tc) {
    floatx4 acc2 = {b2v, b2v, b2v, b2v};            // bias in C-in
#pragma unroll
    for (int s8 = 0; s8 < 8; ++s8) {
      int r = r0 + l15;
      int bo = r * 512 + 64 * s8 + 16 * l4;
      bo ^= (r & 7) << 4;
      short8 a2 = *(const short8*)((const char*)sCr + bo);
      acc2 = __builtin_amdgcn_mfma_f32_16x16x32_bf16(a2, w2f[s8], acc2, 0, 0, 0);
    }
    long nodebase = (long)g0 * NPG + tc * TILE_ROWS + r0 + 4 * l4;
    if (c0 == 0) {          // wave-uniform: cols 0..15 = d(0,1) + U(0..13)
#pragma unroll
      for (int q = 0; q < 4; ++q) {
        float v = acc2[q];
        long node = nodebase + q;
        if (l15 < 2) outD[node * 2 + l15] = softplusf(v);
        else         outU[node * 16 + (l15 - 2)] = v;
      }
    } else {                // cols 16..31 = U(14,15) + pad
#pragma unroll
      for (int q = 0; q < 4; ++q) {
        long node = nodebase + q;
        if (l15 < 2) outU[node * 16 + 14 + l15] = acc2[q];
      }
    }
  };

  // body: A(t)->sHw ; bar ; [C(t-1) from sCr] ; B(t)->sCw
  auto body = [&](float4 (&cur)[4], unsigned short* sHw,
                  const unsigned short* sCr, unsigned short* sCw, int t) {
    // ---- Region A: consume prefetched regs -> pool partials + bf16 swizzled sHw ----
#pragma unroll
    for (int i = 0; i < 4; ++i) {
      float4 v = cur[i];
      psum.x += v.x; psum.y += v.y; psum.z += v.z; psum.w += v.w;
      int row = i * 8 + (tid >> 5);
      int bo = row * 256 + (tid & 31) * 8;
      bo ^= (row & 7) << 4;
      uint2 p;
      p.x = cvt_pk_bf16(v.x, v.y);
      p.y = cvt_pk_bf16(v.z, v.w);
      *(uint2*)((char*)sHw + bo) = p;
    }
    if (t == 31) { pool0 = psum; psum = make_float4(0.f, 0.f, 0.f, 0.f); }  // graph boundary
    if (t + 2 < TILES_PER_WG) {
      const float* nb = Hb + (t + 2) * (TILE_ROWS * HID);
#pragma unroll
      for (int i = 0; i < 4; ++i) cur[i] = *(const float4*)(nb + i * 1024 + tid * 4);
    }
    wg_barrier_lds();   // the ONLY barrier this tile

    // ---- Region C of previous tile (overlaps B's LDS reads in the schedule) ----
    if (t > 0) regionC(sCr, t - 1);

    // ---- Region B: layer-1 MFMA (weights in regs, bias in C-in) + DPP epilogue ----
    floatx4 acc[2][4];
#pragma unroll
    for (int mt = 0; mt < 2; ++mt)
#pragma unroll
      for (int nt = 0; nt < 4; ++nt)
        acc[mt][nt] = (floatx4){b1b[nt], b1b[nt], b1b[nt], b1b[nt]};

#pragma unroll
    for (int ks = 0; ks < 4; ++ks) {
      short8 a[2];
#pragma unroll
      for (int mt = 0; mt < 2; ++mt) {
        int row = 16 * mt + l15;
        int bo = row * 256 + 64 * ks + 16 * l4;
        bo ^= (row & 7) << 4;
        a[mt] = *(const short8*)((const char*)sHw + bo);
      }
#pragma unroll
      for (int mt = 0; mt < 2; ++mt)
#pragma unroll
        for (int nt = 0; nt < 4; ++nt)
          acc[mt][nt] = __builtin_amdgcn_mfma_f32_16x16x32_bf16(a[mt], b1f[nt][ks], acc[mt][nt], 0, 0, 0);
    }

    // Epilogue: per 4x4 quad sub-block, transpose in VALU, one ds_write_b64.
#pragma unroll
    for (int mt = 0; mt < 2; ++mt) {
#pragma unroll
      for (int nt = 0; nt < 4; ++nt) {
        float v0 = fmaxf(acc[mt][nt][0], 0.f);
        float v1 = fmaxf(acc[mt][nt][1], 0.f);
        float v2 = fmaxf(acc[mt][nt][2], 0.f);
        float v3 = fmaxf(acc[mt][nt][3], 0.f);
        unsigned A = cvt_pk_bf16(v0, v1);          // rows q0,q1 (own col)
        unsigned B = cvt_pk_bf16(v2, v3);          // rows q2,q3
        unsigned An = (unsigned)__builtin_amdgcn_mov_dpp((int)A, 0xB1, 0xF, 0xF, true); // lane^1
        unsigned Bn = (unsigned)__builtin_amdgcn_mov_dpp((int)B, 0xB1, 0xF, 0xF, true);
        unsigned WA = __builtin_amdgcn_perm(An, A, selw);
        unsigned WB = __builtin_amdgcn_perm(Bn, B, selw);
        unsigned WAs = (unsigned)__builtin_amdgcn_mov_dpp((int)WA, 0x4E, 0xF, 0xF, true); // lane^2
        unsigned WBs = (unsigned)__builtin_amdgcn_mov_dpp((int)WB, 0x4E, 0xF, 0xF, true);
        uint2 o;
        o.x = hi2 ? WBs : WA;
        o.y = hi2 ? WB  : WAs;
        int row = 16 * mt + 4 * l4 + (l15 & 3);
        int cb  = 64 * w + 16 * nt + (l15 & 12);
        int bo = row * 512 + cb * 2;
        bo ^= (row & 7) << 4;
        *(uint2*)((char*)sCw + bo) = o;
      }
    }
    // no trailing barrier: next tile's bar orders sCw writes vs C(t) reads
  };

  for (int t = 0; t < TILES_PER_WG; t += 2) {
    body(svA, sH0, sC1b, sC1a, t);       // even tile: stage sH0, C(t-1)<-sC1b, B->sC1a
    body(svB, sH1, sC1a, sC1b, t + 1);   // odd  tile: stage sH1, C(t-1)<-sC1a, B->sC1b
  }
  wg_barrier_lds();
  regionC(sC1b, TILES_PER_WG - 1);   // drain tile 63 (odd -> sC1b)

  // ---- tails: s-head per graph (exact f32) ----
  auto tail = [&](float4 p, int g) {
    __syncthreads();
    p.x += __shfl_xor(p.x, 32);
    p.y += __shfl_xor(p.y, 32);
    p.z += __shfl_xor(p.z, 32);
    p.w += __shfl_xor(p.w, 32);
    if (lane < 32) *(float4*)&sX[w * 128 + lane * 4] = p;   // per-wave col partials
    __syncthreads();
    if (tid < 128) {                      // pool[c] = sum over 4 waves
      float pc = sX[tid] + sX[128 + tid] + sX[256 + tid] + sX[384 + tid];
      sX[512 + tid] = pc;
    }
    __syncthreads();
    if (tid < 128) {
      float a = s_b1[tid];
      const float inv = 1.f / 1024.f;
#pragma unroll 8
      for (int k = 0; k < 128; ++k)
        a = fmaf(sX[512 + k] * inv, s_w1[k * 128 + tid], a);
      sX[640 + tid] = fmaxf(a, 0.f);
    }
    __syncthreads();
    if (tid < 8) {
      float a = s_b2[tid];
#pragma unroll 8
      for (int h = 0; h < 128; ++h)
        a = fmaf(sX[640 + h], s_w2[h * 8 + tid], a);
      outS[(long)g * 8 + tid] = softplusf(a);
    }
  };
  tail(pool0, g0);
  tail(psum,  g0 + 1);
}

// ---------------------------------------------------------------------------
extern "C" void kernel_launch(void* const* d_in, const int* in_sizes, int n_in,
                              void* d_out, int out_size, void* d_ws, size_t ws_size,
                              hipStream_t stream)
{
  const float* H    = (const float*)d_in[0];
  // d_in[1] = batch (int32) — equal sorted segments, structure is assumed
  const float* d_w1 = (const float*)d_in[2];
  const float* d_b1 = (const float*)d_in[3];
  const float* d_w2 = (const float*)d_in[4];
  const float* d_b2 = (const float*)d_in[5];
  const float* u_w1 = (const float*)d_in[6];
  const float* u_b1 = (const float*)d_in[7];
  const float* u_w2 = (const float*)d_in[8];
  const float* u_b2 = (const float*)d_in[9];
  const float* s_w1 = (const float*)d_in[10];
  const float* s_b1 = (const float*)d_in[11];
  const float* s_w2 = (const float*)d_in[12];
  const float* s_b2 = (const float*)d_in[13];

  unsigned short* Wt1   = (unsigned short*)d_ws;
  unsigned short* W2t   = (unsigned short*)((char*)d_ws + 65536);
  float*          b1cat = (float*)((char*)d_ws + 81920);
  float*          b2cat = (float*)((char*)d_ws + 82944);

  hipLaunchKernelGGL(prep_kernel, dim3(64), dim3(256), 0, stream,
                     d_w1, d_b1, d_w2, u_w1, u_b1, u_w2, d_b2, u_b2,
                     Wt1, W2t, b1cat, b2cat);

  hipLaunchKernelGGL(fused_kernel, dim3(G_NUM / GRAPHS_PER_WG), dim3(256), 0, stream,
                     H, Wt1, W2t, b1cat, b2cat, s_w1, s_b1, s_w2, s_b2,
                     (float*)d_out);
}